// Round 1
// baseline (112.293 us; speedup 1.0000x reference)
//
#include <hip/hip_runtime.h>

// Problem: out[i] = sum_k targets[i,k] * temporal_bases[batch_indices[1],k] * scaling[k]
// B=8192, K=1024, T=16384. Pure matvec; HBM-bound on the 33.6 MB `targets` read
// (L3 is flushed each iteration by the harness's 256 MiB workspace poison-fill).
//
// Structure: 4 rows per wave, 4 waves per block (256 thr) -> 16 rows/block,
// grid = 512 blocks (2 blocks/CU). Each lane owns k = j*256 + lane*4 (j=0..3).
// w[k] = wrow[k]*scaling[k] is loaded ONCE per wave into 16 VGPRs, then 16
// independent dwordx4 target loads are issued back-to-back (16 KB MLP/wave,
// 128 KB in flight per CU) before any FMA. This removes the 2/3 of issued
// loads that were redundant cached streams and amortizes the shuffle-reduce
// tail over 4 rows.

#define KDIM 1024
#define ROWS_PER_WAVE 4
#define WAVES_PER_BLOCK 4
#define ROWS_PER_BLOCK (ROWS_PER_WAVE * WAVES_PER_BLOCK)  // 16

__global__ __launch_bounds__(256) void recompose_col1_kernel(
    const float* __restrict__ targets,        // (B, K)
    const float* __restrict__ temporal_bases, // (T, K)
    const float* __restrict__ scaling,        // (K,)
    const int*   __restrict__ batch_indices,  // (B,)
    float*       __restrict__ out)            // (B,)
{
    const int wave = threadIdx.x >> 6;   // 0..3
    const int lane = threadIdx.x & 63;
    const int row0 = blockIdx.x * ROWS_PER_BLOCK + wave * ROWS_PER_WAVE;

    const long long sel = (long long)batch_indices[1];
    const float* __restrict__ wrow = temporal_bases + sel * (long long)KDIM;

    // Per-lane K-slice: k = j*256 + lane*4. Fold scaling into w once per wave.
    float4 w[4];
    #pragma unroll
    for (int j = 0; j < 4; ++j) {
        const int k = (j << 8) + (lane << 2);
        const float4 b = *(const float4*)(wrow + k);
        const float4 s = *(const float4*)(scaling + k);
        w[j] = make_float4(b.x * s.x, b.y * s.y, b.z * s.z, b.w * s.w);
    }

    // Issue all 16 target loads (4 rows x 4 dwordx4) before any use:
    // each load is a contiguous 64-lane x 16 B = 1 KiB coalesced segment.
    float4 a[ROWS_PER_WAVE][4];
    #pragma unroll
    for (int r = 0; r < ROWS_PER_WAVE; ++r) {
        const float* __restrict__ trow =
            targets + (long long)(row0 + r) * (long long)KDIM;
        #pragma unroll
        for (int j = 0; j < 4; ++j)
            a[r][j] = *(const float4*)(trow + ((j << 8) + (lane << 2)));
    }

    float acc[ROWS_PER_WAVE];
    #pragma unroll
    for (int r = 0; r < ROWS_PER_WAVE; ++r) {
        float s = 0.0f;
        #pragma unroll
        for (int j = 0; j < 4; ++j) {
            s += a[r][j].x * w[j].x;
            s += a[r][j].y * w[j].y;
            s += a[r][j].z * w[j].z;
            s += a[r][j].w * w[j].w;
        }
        acc[r] = s;
    }

    // 4 independent 64-lane butterfly reductions (interleaved for ILP).
    #pragma unroll
    for (int off = 32; off > 0; off >>= 1) {
        #pragma unroll
        for (int r = 0; r < ROWS_PER_WAVE; ++r)
            acc[r] += __shfl_down(acc[r], off, 64);
    }

    if (lane == 0) {
        #pragma unroll
        for (int r = 0; r < ROWS_PER_WAVE; ++r)
            out[row0 + r] = acc[r];
    }
}

extern "C" void kernel_launch(void* const* d_in, const int* in_sizes, int n_in,
                              void* d_out, int out_size, void* d_ws, size_t ws_size,
                              hipStream_t stream) {
    const float* targets        = (const float*)d_in[0];
    const float* temporal_bases = (const float*)d_in[1];
    const float* scaling        = (const float*)d_in[2];
    const int*   batch_indices  = (const int*)d_in[3];
    float*       out            = (float*)d_out;

    const int B = in_sizes[0] / KDIM;              // 8192
    const int blocks = B / ROWS_PER_BLOCK;         // 512
    recompose_col1_kernel<<<blocks, 256, 0, stream>>>(
        targets, temporal_bases, scaling, batch_indices, out);
}